// Round 1
// baseline (1267.405 us; speedup 1.0000x reference)
//
#include <hip/hip_runtime.h>
#include <stdint.h>

typedef _Float16 f16;
typedef _Float16 half2_t __attribute__((ext_vector_type(2)));
typedef _Float16 half8_t __attribute__((ext_vector_type(8)));
typedef float    f32x4_t __attribute__((ext_vector_type(4)));

constexpr int NB = 64, NS = 512, NT = 256, NE = 256, NH = 256;
constexpr int G3 = 768;  // 3*NH

static __device__ __forceinline__ float sigm(float x){ return 1.f/(1.f+__expf(-x)); }
static __device__ __forceinline__ float tanhfast(float x){
  float e = __expf(-2.f*x);
  return (1.f-e)/(1.f+e);
}
static __device__ __forceinline__ uint32_t pack2(float a, float b){
  half2_t h; h[0]=(f16)a; h[1]=(f16)b;
  return __builtin_bit_cast(uint32_t, h);
}
static __device__ __forceinline__ float dot2f(uint32_t w, uint32_t h, float acc){
#if __has_builtin(__builtin_amdgcn_fdot2)
  return __builtin_amdgcn_fdot2(__builtin_bit_cast(half2_t,w),
                                __builtin_bit_cast(half2_t,h), acc, false);
#else
  half2_t a = __builtin_bit_cast(half2_t,w), b = __builtin_bit_cast(half2_t,h);
  return acc + (float)a[0]*(float)b[0] + (float)a[1]*(float)b[1];
#endif
}
static __device__ __forceinline__ half8_t cvt8(float4 a, float4 b){
  half8_t p;
  p[0]=(f16)a.x; p[1]=(f16)a.y; p[2]=(f16)a.z; p[3]=(f16)a.w;
  p[4]=(f16)b.x; p[5]=(f16)b.y; p[6]=(f16)b.z; p[7]=(f16)b.w;
  return p;
}

// ---------- prep: Wh (768x256 f32) -> packed-half2, transposed [128 kp][768 row]
__global__ __launch_bounds__(256) void k_prep_whT(const float* __restrict__ Wh,
                                                  uint32_t* __restrict__ out){
  int idx = blockIdx.x*256 + threadIdx.x;      // 98304 total
  int kp = idx / G3, row = idx % G3;
  float a = Wh[(size_t)row*NE + 2*kp];
  float b = Wh[(size_t)row*NE + 2*kp + 1];
  out[idx] = pack2(a, b);
}

// ---------- prep: decoder input tokens
__global__ __launch_bounds__(256) void k_in_toks(const int* __restrict__ pre_seq,
                                                 const int* __restrict__ trg,
                                                 int* __restrict__ out){
  int idx = blockIdx.x*256 + threadIdx.x;      // 16384
  int b = idx >> 8, t = idx & 255;
  out[idx] = (t == 0) ? pre_seq[b*NS + NS-1] : trg[b*NT + t - 1];
}

// ---------- gi GEMM: out[m][n] = emb[toks[m]][:] . Wi[n][:] + bi[n]   (f16 out)
// tile 128x128, BK=64, 256 threads, 2x2 waves each 64x64
__global__ __launch_bounds__(256) void k_gemm_gi(const float* __restrict__ emb,
                                                 const int* __restrict__ toks,
                                                 const float* __restrict__ Wi,
                                                 const float* __restrict__ bi,
                                                 f16* __restrict__ out){
  __shared__ f16 As[128][72];
  __shared__ f16 Bs[128][72];
  const int tid = threadIdx.x;
  const int m0 = blockIdx.x*128, n0 = blockIdx.y*128;
  const int lane = tid & 63, wid = tid >> 6;
  const int wm = wid >> 1, wn = wid & 1;
  const int fr = lane & 15, fq = lane >> 4;

  f32x4_t acc[4][4];
  #pragma unroll
  for (int i=0;i<4;++i)
    #pragma unroll
    for (int j=0;j<4;++j){ acc[i][j][0]=0.f; acc[i][j][1]=0.f; acc[i][j][2]=0.f; acc[i][j][3]=0.f; }

  const int r = tid >> 1, hh = tid & 1;
  const int tok = toks[m0 + r];
  const float* asrc = emb + (size_t)tok*NE + hh*32;
  const float* bsrc = Wi  + (size_t)(n0 + r)*NE + hh*32;

  for (int k0 = 0; k0 < NE; k0 += 64){
    #pragma unroll
    for (int c=0;c<4;++c){
      float4 x0 = *(const float4*)(asrc + k0 + c*8);
      float4 x1 = *(const float4*)(asrc + k0 + c*8 + 4);
      *(half8_t*)&As[r][hh*32 + c*8] = cvt8(x0, x1);
      float4 y0 = *(const float4*)(bsrc + k0 + c*8);
      float4 y1 = *(const float4*)(bsrc + k0 + c*8 + 4);
      *(half8_t*)&Bs[r][hh*32 + c*8] = cvt8(y0, y1);
    }
    __syncthreads();
    #pragma unroll
    for (int kk=0; kk<2; ++kk){
      half8_t af[4], bf[4];
      #pragma unroll
      for (int m=0;m<4;++m) af[m] = *(const half8_t*)&As[wm*64 + m*16 + fr][kk*32 + fq*8];
      #pragma unroll
      for (int n=0;n<4;++n) bf[n] = *(const half8_t*)&Bs[wn*64 + n*16 + fr][kk*32 + fq*8];
      #pragma unroll
      for (int m=0;m<4;++m)
        #pragma unroll
        for (int n=0;n<4;++n)
          acc[m][n] = __builtin_amdgcn_mfma_f32_16x16x32_f16(af[m], bf[n], acc[m][n], 0,0,0);
    }
    __syncthreads();
  }
  // epilogue: C/D layout col=lane&15, row=(lane>>4)*4+reg
  #pragma unroll
  for (int n=0;n<4;++n){
    const int col = n0 + wn*64 + n*16 + fr;
    const float bv = bi[col];
    #pragma unroll
    for (int m=0;m<4;++m){
      const int rowb = m0 + wm*64 + m*16 + fq*4;
      #pragma unroll
      for (int j=0;j<4;++j)
        out[(size_t)(rowb + j)*G3 + col] = (f16)(acc[m][n][j] + bv);
    }
  }
}

// ---------- encoder recurrence: 128 blocks = (batch 64) x (pre/post)
// 512 threads: n = tid&255 hidden dim, half = tid>>8 K-half. Weights in VGPRs.
__global__ __launch_bounds__(512, 2) void k_enc(const uint32_t* __restrict__ WhT_pre,
                                                const uint32_t* __restrict__ WhT_post,
                                                const f16* __restrict__ gi_pre,
                                                const f16* __restrict__ gi_post,
                                                const float* __restrict__ bh_pre,
                                                const float* __restrict__ bh_post,
                                                const float* __restrict__ w_hid,
                                                float* __restrict__ Abuf,
                                                float* __restrict__ preh,
                                                float* __restrict__ posth){
  __shared__ __align__(16) uint32_t h_pair[128];
  __shared__ float part[3][256];
  __shared__ float ared[4];

  const int b = blockIdx.x & 63, which = blockIdx.x >> 6;
  const int tid = threadIdx.x;
  const int n = tid & 255, half = tid >> 8;

  const uint32_t* WhT = which ? WhT_post : WhT_pre;
  const f16* gi = (which ? gi_post : gi_pre) + (size_t)b*NS*G3;
  const float* bh = which ? bh_post : bh_pre;

  uint32_t w[192];
  {
    const uint32_t* wsrc = WhT + (size_t)(half*64)*G3 + n;
    #pragma unroll
    for (int i=0;i<192;++i){
      int g = i >> 6, k2 = i & 63;
      w[i] = wsrc[(size_t)k2*G3 + g*256];
    }
  }
  const float bh0 = bh[n], bh1 = bh[256+n], bh2 = bh[512+n];
  const float whv = w_hid[n];
  float hreg = 0.f;
  if (tid < 128) h_pair[tid] = 0u;
  __syncthreads();

  float* Arow = Abuf + b*1024 + which*512;

  for (int t=0; t<NS; ++t){
    float g0=0.f, g1=0.f, g2=0.f;
    if (half == 0){
      const f16* gp = gi + (size_t)t*G3;
      g0 = (float)gp[n]; g1 = (float)gp[256+n]; g2 = (float)gp[512+n];
    }
    float a0=0.f, a1=0.f, a2=0.f;
    const uint32_t* hp = h_pair + half*64;
    #pragma unroll
    for (int c=0;c<8;++c){
      uint32_t hc[8];
      *(uint4*)&hc[0] = *(const uint4*)(hp + c*8);
      *(uint4*)&hc[4] = *(const uint4*)(hp + c*8 + 4);
      #pragma unroll
      for (int i=0;i<8;++i){
        a0 = dot2f(w[      c*8+i], hc[i], a0);
        a1 = dot2f(w[ 64 + c*8+i], hc[i], a1);
        a2 = dot2f(w[128 + c*8+i], hc[i], a2);
      }
    }
    if (half == 1){ part[0][n]=a0; part[1][n]=a1; part[2][n]=a2; }
    __syncthreads();
    if (half == 0){
      float ghr = a0 + part[0][n] + bh0;
      float ghz = a1 + part[1][n] + bh1;
      float ghn = a2 + part[2][n] + bh2;
      float rg = sigm(g0 + ghr);
      float zg = sigm(g1 + ghz);
      float nn = tanhfast(g2 + rg*ghn);
      float hnew = (1.f - zg)*nn + zg*hreg;
      hreg = hnew;
      float hnb = __shfl_down(hnew, 1);
      if ((n & 1) == 0) h_pair[n >> 1] = pack2(hnew, hnb);
      float redv = fmaxf(hnew, 0.f) * whv;
      #pragma unroll
      for (int off=32; off; off>>=1) redv += __shfl_down(redv, off);
      if ((tid & 63) == 0) ared[tid >> 6] = redv;
    }
    __syncthreads();
    if (tid == 0) Arow[t] = ared[0]+ared[1]+ared[2]+ared[3];
  }
  if (half == 0) (which ? posth : preh)[b*NH + n] = hreg;
}

// ---------- decoder recurrence (h0 = tanh(Wfc.[preh;posth]+bfc) fused)
__global__ __launch_bounds__(512, 2) void k_dec(const uint32_t* __restrict__ WhT,
                                                const f16* __restrict__ gi,
                                                const float* __restrict__ bh,
                                                const float* __restrict__ w_hid,
                                                const float* __restrict__ Wfc,
                                                const float* __restrict__ bfc,
                                                const float* __restrict__ preh,
                                                const float* __restrict__ posth,
                                                float* __restrict__ sbuf){
  __shared__ __align__(16) uint32_t h_pair[128];
  __shared__ float part[3][256];
  __shared__ float ared[4];
  __shared__ float hcat[512];

  const int b = blockIdx.x;
  const int tid = threadIdx.x;
  const int n = tid & 255, half = tid >> 8;

  uint32_t w[192];
  {
    const uint32_t* wsrc = WhT + (size_t)(half*64)*G3 + n;
    #pragma unroll
    for (int i=0;i<192;++i){
      int g = i >> 6, k2 = i & 63;
      w[i] = wsrc[(size_t)k2*G3 + g*256];
    }
  }
  const float bh0 = bh[n], bh1 = bh[256+n], bh2 = bh[512+n];
  const float whv = w_hid[NH + n];
  float hreg = 0.f;

  // h0
  hcat[tid] = (tid < 256) ? preh[b*NH + tid] : posth[b*NH + tid - 256];
  __syncthreads();
  {
    const float* wrow = Wfc + (size_t)n*512 + half*256;
    const float* hc = hcat + half*256;
    float acc = 0.f;
    #pragma unroll 8
    for (int j=0;j<256;j+=4){
      float4 wv = *(const float4*)(wrow + j);
      acc = fmaf(wv.x, hc[j],   acc);
      acc = fmaf(wv.y, hc[j+1], acc);
      acc = fmaf(wv.z, hc[j+2], acc);
      acc = fmaf(wv.w, hc[j+3], acc);
    }
    if (half == 1) part[0][n] = acc;
    __syncthreads();
    if (half == 0){
      float h0 = tanhfast(acc + part[0][n] + bfc[n]);
      hreg = h0;
      float hnb = __shfl_down(h0, 1);
      if ((n & 1) == 0) h_pair[n >> 1] = pack2(h0, hnb);
    }
    __syncthreads();
  }

  const f16* gib = gi + (size_t)b*NT*G3;
  for (int t=0; t<NT; ++t){
    float g0=0.f, g1=0.f, g2=0.f;
    if (half == 0){
      const f16* gp = gib + (size_t)t*G3;
      g0 = (float)gp[n]; g1 = (float)gp[256+n]; g2 = (float)gp[512+n];
    }
    float a0=0.f, a1=0.f, a2=0.f;
    const uint32_t* hp = h_pair + half*64;
    #pragma unroll
    for (int c=0;c<8;++c){
      uint32_t hc8[8];
      *(uint4*)&hc8[0] = *(const uint4*)(hp + c*8);
      *(uint4*)&hc8[4] = *(const uint4*)(hp + c*8 + 4);
      #pragma unroll
      for (int i=0;i<8;++i){
        a0 = dot2f(w[      c*8+i], hc8[i], a0);
        a1 = dot2f(w[ 64 + c*8+i], hc8[i], a1);
        a2 = dot2f(w[128 + c*8+i], hc8[i], a2);
      }
    }
    if (half == 1){ part[0][n]=a0; part[1][n]=a1; part[2][n]=a2; }
    __syncthreads();
    if (half == 0){
      float ghr = a0 + part[0][n] + bh0;
      float ghz = a1 + part[1][n] + bh1;
      float ghn = a2 + part[2][n] + bh2;
      float rg = sigm(g0 + ghr);
      float zg = sigm(g1 + ghz);
      float nn = tanhfast(g2 + rg*ghn);
      float hnew = (1.f - zg)*nn + zg*hreg;
      hreg = hnew;
      float hnb = __shfl_down(hnew, 1);
      if ((n & 1) == 0) h_pair[n >> 1] = pack2(hnew, hnb);
      float redv = fmaxf(hnew, 0.f) * whv;
      #pragma unroll
      for (int off=32; off; off>>=1) redv += __shfl_down(redv, off);
      if ((tid & 63) == 0) ared[tid >> 6] = redv;
    }
    __syncthreads();
    if (tid == 0) sbuf[b*NT + t] = ared[0]+ared[1]+ared[2]+ared[3];
  }
}

// ---------- final expansion: out[b,t,j] = (A[b,j] + s[b,t] + b_hid)*w_out + b_out
__global__ __launch_bounds__(256) void k_final(const float* __restrict__ Abuf,
                                               const float* __restrict__ sbuf,
                                               const float* __restrict__ b_hid,
                                               const float* __restrict__ w_out,
                                               const float* __restrict__ b_out,
                                               float* __restrict__ out){
  const float bh = b_hid[0], wo = w_out[0], bo = b_out[0];
  const int idx = blockIdx.x*256 + threadIdx.x;       // 2,097,152
  const int j4 = idx & 127, t = (idx >> 7) & 255, b = idx >> 15;
  const float sv = sbuf[b*NT + t] + bh;
  const float4 a0 = *(const float4*)(Abuf + b*1024 + j4*4);
  const float4 a1 = *(const float4*)(Abuf + b*1024 + 512 + j4*4);
  float4 o0, o1;
  o0.x = (a0.x + sv)*wo + bo; o0.y = (a0.y + sv)*wo + bo;
  o0.z = (a0.z + sv)*wo + bo; o0.w = (a0.w + sv)*wo + bo;
  o1.x = (a1.x + sv)*wo + bo; o1.y = (a1.y + sv)*wo + bo;
  o1.z = (a1.z + sv)*wo + bo; o1.w = (a1.w + sv)*wo + bo;
  float4* o = (float4*)out;
  o[idx] = o0;
  o[(size_t)(NB*NT*NS/4) + idx] = o1;
}

extern "C" void kernel_launch(void* const* d_in, const int* in_sizes, int n_in,
                              void* d_out, int out_size, void* d_ws, size_t ws_size,
                              hipStream_t stream){
  const int*   pre_seq = (const int*)d_in[0];
  const int*   post_seq= (const int*)d_in[1];
  const int*   trg     = (const int*)d_in[2];
  const float* emb     = (const float*)d_in[3];
  const float* Wi_pre  = (const float*)d_in[4];
  const float* Wh_pre  = (const float*)d_in[5];
  const float* bi_pre  = (const float*)d_in[6];
  const float* bh_pre  = (const float*)d_in[7];
  const float* Wi_post = (const float*)d_in[8];
  const float* Wh_post = (const float*)d_in[9];
  const float* bi_post = (const float*)d_in[10];
  const float* bh_post = (const float*)d_in[11];
  const float* Wfc     = (const float*)d_in[12];
  const float* bfc     = (const float*)d_in[13];
  const float* Wi_dec  = (const float*)d_in[14];
  const float* Wh_dec  = (const float*)d_in[15];
  const float* bi_dec  = (const float*)d_in[16];
  const float* bh_dec  = (const float*)d_in[17];
  const float* w_hid   = (const float*)d_in[18];
  const float* b_hid   = (const float*)d_in[19];
  const float* w_out   = (const float*)d_in[20];
  const float* b_out   = (const float*)d_in[21];

  char* wp = (char*)d_ws;
  f16* gi_pre  = (f16*)wp; wp += (size_t)NB*NS*G3*2;   // 50.3 MB
  f16* gi_post = (f16*)wp; wp += (size_t)NB*NS*G3*2;   // 50.3 MB
  f16* gi_dec  = (f16*)wp; wp += (size_t)NB*NT*G3*2;   // 25.2 MB
  uint32_t* WhT_pre  = (uint32_t*)wp; wp += (size_t)128*G3*4;
  uint32_t* WhT_post = (uint32_t*)wp; wp += (size_t)128*G3*4;
  uint32_t* WhT_dec  = (uint32_t*)wp; wp += (size_t)128*G3*4;
  int*   in_toks = (int*)wp;   wp += (size_t)NB*NT*4;
  float* Abuf    = (float*)wp; wp += (size_t)NB*1024*4;
  float* sbuf    = (float*)wp; wp += (size_t)NB*NT*4;
  float* preh    = (float*)wp; wp += (size_t)NB*NH*4;
  float* posth   = (float*)wp; wp += (size_t)NB*NH*4;
  (void)ws_size; (void)in_sizes; (void)n_in; (void)out_size;

  k_prep_whT<<<384, 256, 0, stream>>>(Wh_pre,  WhT_pre);
  k_prep_whT<<<384, 256, 0, stream>>>(Wh_post, WhT_post);
  k_prep_whT<<<384, 256, 0, stream>>>(Wh_dec,  WhT_dec);
  k_in_toks <<<64, 256, 0, stream>>>(pre_seq, trg, in_toks);

  k_gemm_gi<<<dim3(256,6), 256, 0, stream>>>(emb, pre_seq,  Wi_pre,  bi_pre,  gi_pre);
  k_gemm_gi<<<dim3(256,6), 256, 0, stream>>>(emb, post_seq, Wi_post, bi_post, gi_post);
  k_gemm_gi<<<dim3(128,6), 256, 0, stream>>>(emb, in_toks,  Wi_dec,  bi_dec,  gi_dec);

  k_enc<<<128, 512, 0, stream>>>(WhT_pre, WhT_post, gi_pre, gi_post,
                                 bh_pre, bh_post, w_hid, Abuf, preh, posth);
  k_dec<<<64, 512, 0, stream>>>(WhT_dec, gi_dec, bh_dec, w_hid, Wfc, bfc,
                                preh, posth, sbuf);
  k_final<<<NB*NT*NS/4/256, 256, 0, stream>>>(Abuf, sbuf, b_hid, w_out, b_out,
                                              (float*)d_out);
}